// Round 3
// baseline (1333.907 us; speedup 1.0000x reference)
//
#include <hip/hip_runtime.h>
#include <cstdint>

#define N_NODES 65536
#define E_EDGES 524288

typedef unsigned short u16;
typedef unsigned int u32;
typedef __attribute__((ext_vector_type(8))) short bf16x8;
typedef __attribute__((ext_vector_type(4))) float f32x4;

__device__ __forceinline__ float fast_sigmoid(float x) { return 1.0f / (1.0f + __expf(-x)); }
__device__ __forceinline__ float fast_tanh(float x) { return 1.0f - 2.0f / (__expf(2.0f * x) + 1.0f); }

__device__ __forceinline__ u16 f2bf(float f) {
    u32 u = __builtin_bit_cast(u32, f);
    u32 r = u + 0x7fffu + ((u >> 16) & 1u);
    return (u16)(r >> 16);
}

// XOR swizzle: permute 16B slots within a row by (row&7) — kills stride-128/256B bank conflicts
#define SWZ(row, byte) ((byte) ^ (((row) & 7) << 4))

// ---------- prep: fp32->bf16 conversions ----------
__global__ void cvt_inputs(const float* __restrict__ nf, const float* __restrict__ W1,
                           const float* __restrict__ W2,
                           u16* __restrict__ nf_bf, u16* __restrict__ W1bf, u16* __restrict__ W2bf)
{
    int u = blockIdx.x * 256 + threadIdx.x;
    const float4* srcp; u16* dstp; int idx;
    if (u < 2097152)            { srcp = (const float4*)nf; dstp = nf_bf; idx = u; }
    else if ((u -= 2097152) < 10240) { srcp = (const float4*)W1; dstp = W1bf; idx = u; }
    else if ((u -= 10240) < 4096)    { srcp = (const float4*)W2; dstp = W2bf; idx = u; }
    else return;
    float4 f = srcp[idx];
    uint2 pk;
    pk.x = (u32)f2bf(f.x) | ((u32)f2bf(f.y) << 16);
    pk.y = (u32)f2bf(f.z) | ((u32)f2bf(f.w) << 16);
    *(uint2*)(dstp + (size_t)idx * 4) = pk;
}

// ---------- prep: transpose GRU weights into k-major ----------
__global__ void prep_weights(const float* __restrict__ Wih, const float* __restrict__ Whh,
                             float* __restrict__ WihT, float* __restrict__ WhhT)
{
    int idx = blockIdx.x * 256 + threadIdx.x;
    if (idx < 256 * 384) { int k = idx / 384, o = idx - k * 384; WihT[idx] = Wih[o * 256 + k]; return; }
    idx -= 256 * 384;
    if (idx < 128 * 384) { int k = idx / 384, o = idx - k * 384; WhhT[idx] = Whh[o * 128 + k]; }
}

// ---------- edge MLP via bf16 MFMA + atomic scatter ----------
// Block: 128 edges x 128 outs, 256 threads = 4 waves (2x2), wave tile 64x64 (4x4 frags 16x16x32).
// Stage1: cat(320) @ W1^T -> relu -> hid in LDS (bf16). Stage2: hid @ W2^T -> atomicAdd to m.
__global__ __launch_bounds__(256) void edge_mlp_mfma(
    const u16* __restrict__ nf_bf, const float* __restrict__ ef,
    const int* __restrict__ src, const int* __restrict__ dst,
    const u16* __restrict__ W1bf, const float* __restrict__ b1,
    const u16* __restrict__ W2bf, const float* __restrict__ b2,
    float* __restrict__ m_out)
{
    __shared__ __align__(16) char smem[65536];
    __shared__ int sNode[2][128];           // [0]=src, [1]=dst
    char* sA   = smem;                      // [128][64] bf16, 128B rows (stage1 A)
    char* sB   = smem + 16384;              // [128][64] bf16 (stage1 B: W1 [o][k]-chunk)
    char* sHid = smem + 32768;              // [128][128] bf16, 256B rows
    char* sB2  = smem;                      // [128][128] bf16 (stage2 B, reuses sA+sB)

    const int tid = threadIdx.x;
    const int lane = tid & 63;
    const int wv = tid >> 6;
    const int wm = wv >> 1, wn = wv & 1;
    const int q = lane >> 4, r16 = lane & 15;
    const int e0 = blockIdx.x * 128;

    if (tid < 128) sNode[0][tid] = src[e0 + tid];
    else           sNode[1][tid - 128] = dst[e0 + tid - 128];

    float b1v[4], b2v[4];
    #pragma unroll
    for (int ni = 0; ni < 4; ++ni) {
        int o = wn * 64 + ni * 16 + r16;
        b1v[ni] = b1[o];
        b2v[ni] = b2[o];
    }

    f32x4 acc[4][4] = {};
    __syncthreads();   // sNode ready

    // ---- stage 1: K=320 in 5 chunks of 64 (4x nf halves, 1x ef) ----
    for (int c = 0; c < 5; ++c) {
        __syncthreads();                    // prior chunk's LDS reads complete
        if (c < 4) {
            const int half = (c & 1) * 64;
            const int* nodes = sNode[c >> 1];
            #pragma unroll
            for (int i = 0; i < 4; ++i) {
                int u = tid + i * 256;      // 0..1023
                int e = u >> 3, part = u & 7;
                int node = nodes[e];
                bf16x8 v = *(const bf16x8*)(nf_bf + (size_t)node * 128 + half + part * 8);
                *(bf16x8*)(sA + SWZ(e, e * 128 + part * 16)) = v;
            }
        } else {
            #pragma unroll
            for (int i = 0; i < 8; ++i) {
                int u = tid + i * 256;      // 0..2047
                int e = u >> 4, part = u & 15;   // 4 floats per unit
                float4 f = *(const float4*)(ef + (size_t)(e0 + e) * 64 + part * 4);
                uint2 pk;
                pk.x = (u32)f2bf(f.x) | ((u32)f2bf(f.y) << 16);
                pk.y = (u32)f2bf(f.z) | ((u32)f2bf(f.w) << 16);
                *(uint2*)(sA + SWZ(e, e * 128 + part * 8)) = pk;
            }
        }
        #pragma unroll
        for (int i = 0; i < 4; ++i) {
            int u = tid + i * 256;
            int o = u >> 3, part = u & 7;
            bf16x8 v = *(const bf16x8*)(W1bf + (size_t)o * 320 + c * 64 + part * 8);
            *(bf16x8*)(sB + SWZ(o, o * 128 + part * 16)) = v;
        }
        __syncthreads();
        #pragma unroll
        for (int ks = 0; ks < 2; ++ks) {
            bf16x8 af[4], bfr[4];
            #pragma unroll
            for (int mi = 0; mi < 4; ++mi) {
                int row = wm * 64 + mi * 16 + r16;
                af[mi] = *(const bf16x8*)(sA + SWZ(row, row * 128 + (ks * 32 + 8 * q) * 2));
            }
            #pragma unroll
            for (int ni = 0; ni < 4; ++ni) {
                int o = wn * 64 + ni * 16 + r16;
                bfr[ni] = *(const bf16x8*)(sB + SWZ(o, o * 128 + (ks * 32 + 8 * q) * 2));
            }
            #pragma unroll
            for (int mi = 0; mi < 4; ++mi)
                #pragma unroll
                for (int ni = 0; ni < 4; ++ni)
                    acc[mi][ni] = __builtin_amdgcn_mfma_f32_16x16x32_bf16(af[mi], bfr[ni], acc[mi][ni], 0, 0, 0);
        }
    }

    // ---- hid = relu(acc + b1) -> sHid (bf16, swizzled) ----
    #pragma unroll
    for (int mi = 0; mi < 4; ++mi)
        #pragma unroll
        for (int ni = 0; ni < 4; ++ni)
            #pragma unroll
            for (int rr = 0; rr < 4; ++rr) {
                int e = wm * 64 + mi * 16 + 4 * q + rr;
                int h = wn * 64 + ni * 16 + r16;
                float v = fmaxf(acc[mi][ni][rr] + b1v[ni], 0.f);
                *(u16*)(sHid + SWZ(e, e * 256 + h * 2)) = f2bf(v);
            }
    __syncthreads();   // hid complete; stage-1 reads of sA/sB complete

    // ---- stage 2 B: W2 [o][k=128] ----
    #pragma unroll
    for (int i = 0; i < 8; ++i) {
        int u = tid + i * 256;
        int o = u >> 4, part = u & 15;
        bf16x8 v = *(const bf16x8*)(W2bf + (size_t)o * 128 + part * 8);
        *(bf16x8*)(sB2 + SWZ(o, o * 256 + part * 16)) = v;
    }
    __syncthreads();

    f32x4 acc2[4][4] = {};
    #pragma unroll
    for (int ks = 0; ks < 4; ++ks) {
        bf16x8 af[4], bfr[4];
        #pragma unroll
        for (int mi = 0; mi < 4; ++mi) {
            int row = wm * 64 + mi * 16 + r16;
            af[mi] = *(const bf16x8*)(sHid + SWZ(row, row * 256 + (ks * 32 + 8 * q) * 2));
        }
        #pragma unroll
        for (int ni = 0; ni < 4; ++ni) {
            int o = wn * 64 + ni * 16 + r16;
            bfr[ni] = *(const bf16x8*)(sB2 + SWZ(o, o * 256 + (ks * 32 + 8 * q) * 2));
        }
        #pragma unroll
        for (int mi = 0; mi < 4; ++mi)
            #pragma unroll
            for (int ni = 0; ni < 4; ++ni)
                acc2[mi][ni] = __builtin_amdgcn_mfma_f32_16x16x32_bf16(af[mi], bfr[ni], acc2[mi][ni], 0, 0, 0);
    }

    // ---- epilogue: msg scatter (fp32 atomics) ----
    #pragma unroll
    for (int mi = 0; mi < 4; ++mi) {
        #pragma unroll
        for (int rr = 0; rr < 4; ++rr) {
            int e = wm * 64 + mi * 16 + 4 * q + rr;
            int d = sNode[1][e];
            float* mrow = m_out + (size_t)d * 128;
            #pragma unroll
            for (int ni = 0; ni < 4; ++ni) {
                int o = wn * 64 + ni * 16 + r16;
                unsafeAtomicAdd(mrow + o, acc2[mi][ni][rr] + b2v[ni]);
            }
        }
    }
}

// ---------- cross-graph attention (flash-style, K=V, two passes) ----------
__global__ __launch_bounds__(256) void attention_kernel(
    const float* __restrict__ nf, float* __restrict__ u)
{
    __shared__ float sK[64][128];

    const int tid = threadIdx.x;
    const int rl = tid >> 2;
    const int quad = tid & 3;
    const int bid = blockIdx.x;
    const int tile = bid & 7;
    const int side = (bid >> 3) & 1;
    const int pair = bid >> 4;

    const float* Qm = nf + ((size_t)pair * 1024 + (size_t)side * 512) * 128;
    const float* Km = nf + ((size_t)pair * 1024 + (size_t)(1 - side) * 512) * 128;

    const int row = tile * 64 + rl;
    float q[32];
    #pragma unroll
    for (int t = 0; t < 8; ++t) {
        float4 v = ((const float4*)Qm)[row * 32 + quad * 8 + t];
        q[t*4+0] = v.x; q[t*4+1] = v.y; q[t*4+2] = v.z; q[t*4+3] = v.w;
    }

    float mmax = -3.0e38f, lsum = 0.f;
    for (int jt = 0; jt < 8; ++jt) {
        __syncthreads();
        #pragma unroll
        for (int t = 0; t < 8; ++t) {
            int w = t * 256 + tid;
            ((float4*)sK)[w] = ((const float4*)Km)[jt * 2048 + w];
        }
        __syncthreads();
        #pragma unroll 4
        for (int j = 0; j < 64; ++j) {
            float s = 0.f;
            #pragma unroll
            for (int t = 0; t < 8; ++t) {
                float4 kv = *(const float4*)&sK[j][quad * 32 + t * 4];
                s = fmaf(q[t*4+0], kv.x, s);
                s = fmaf(q[t*4+1], kv.y, s);
                s = fmaf(q[t*4+2], kv.z, s);
                s = fmaf(q[t*4+3], kv.w, s);
            }
            s += __shfl_xor(s, 1);
            s += __shfl_xor(s, 2);
            float mn = fmaxf(mmax, s);
            lsum = lsum * __expf(mmax - mn) + __expf(s - mn);
            mmax = mn;
        }
    }
    const float invl = 1.f / lsum;

    float acc[32];
    #pragma unroll
    for (int i = 0; i < 32; ++i) acc[i] = 0.f;
    for (int jt = 0; jt < 8; ++jt) {
        __syncthreads();
        #pragma unroll
        for (int t = 0; t < 8; ++t) {
            int w = t * 256 + tid;
            ((float4*)sK)[w] = ((const float4*)Km)[jt * 2048 + w];
        }
        __syncthreads();
        for (int j = 0; j < 64; ++j) {
            float s = 0.f;
            float kr[32];
            #pragma unroll
            for (int t = 0; t < 8; ++t) {
                float4 kv = *(const float4*)&sK[j][quad * 32 + t * 4];
                kr[t*4+0] = kv.x; kr[t*4+1] = kv.y; kr[t*4+2] = kv.z; kr[t*4+3] = kv.w;
                s = fmaf(q[t*4+0], kv.x, s);
                s = fmaf(q[t*4+1], kv.y, s);
                s = fmaf(q[t*4+2], kv.z, s);
                s = fmaf(q[t*4+3], kv.w, s);
            }
            s += __shfl_xor(s, 1);
            s += __shfl_xor(s, 2);
            float p = __expf(s - mmax) * invl;
            #pragma unroll
            for (int t = 0; t < 32; ++t) acc[t] = fmaf(p, kr[t], acc[t]);
        }
    }

    float* up = u + ((size_t)pair * 1024 + (size_t)side * 512 + row) * 128 + quad * 32;
    #pragma unroll
    for (int t = 0; t < 8; ++t) {
        float4 v;
        v.x = q[t*4+0] - acc[t*4+0];
        v.y = q[t*4+1] - acc[t*4+1];
        v.z = q[t*4+2] - acc[t*4+2];
        v.w = q[t*4+3] - acc[t*4+3];
        ((float4*)up)[t] = v;
    }
}

// ---------- GRU cell ----------
__global__ __launch_bounds__(256) void gru_kernel(
    const float* __restrict__ nf, const float* __restrict__ u,
    const float* __restrict__ WihT, const float* __restrict__ bih,
    const float* __restrict__ WhhT, const float* __restrict__ bhh,
    float* __restrict__ out)
{
    __shared__ float sX[32][256];
    __shared__ float sHf[32][128];
    __shared__ float sW[16][384];

    const int tid = threadIdx.x;
    const int lane = tid & 63;
    const int wave = tid >> 6;
    const int n0 = blockIdx.x * 32;

    for (int w = tid; w < 32 * 64; w += 256) {
        int e = w >> 6, c4 = w & 63;
        float4 v;
        if (c4 < 32) v = ((const float4*)out)[(size_t)(n0 + e) * 32 + c4];
        else         v = ((const float4*)u)[(size_t)(n0 + e) * 32 + (c4 - 32)];
        *(float4*)&sX[e][c4 * 4] = v;
    }
    for (int w = tid; w < 32 * 32; w += 256) {
        int e = w >> 5, c4 = w & 31;
        *(float4*)&sHf[e][c4 * 4] = ((const float4*)nf)[(size_t)(n0 + e) * 32 + c4];
    }

    float acc[8][6];
    float acchn[8][2];
    #pragma unroll
    for (int e = 0; e < 8; ++e) {
        #pragma unroll
        for (int t = 0; t < 6; ++t) acc[e][t] = 0.f;
        acchn[e][0] = 0.f; acchn[e][1] = 0.f;
    }

    for (int c = 0; c < 16; ++c) {
        __syncthreads();
        #pragma unroll
        for (int t = 0; t < 6; ++t) {
            int w = t * 256 + tid;
            ((float4*)sW)[w] = ((const float4*)WihT)[c * 1536 + w];
        }
        __syncthreads();
        #pragma unroll
        for (int k = 0; k < 16; ++k) {
            float b[6];
            #pragma unroll
            for (int t = 0; t < 6; ++t) b[t] = sW[k][lane + 64 * t];
            #pragma unroll
            for (int e = 0; e < 8; ++e) {
                float a = sX[wave * 8 + e][c * 16 + k];
                #pragma unroll
                for (int t = 0; t < 6; ++t) acc[e][t] = fmaf(a, b[t], acc[e][t]);
            }
        }
    }
    for (int c = 0; c < 8; ++c) {
        __syncthreads();
        #pragma unroll
        for (int t = 0; t < 6; ++t) {
            int w = t * 256 + tid;
            ((float4*)sW)[w] = ((const float4*)WhhT)[c * 1536 + w];
        }
        __syncthreads();
        #pragma unroll
        for (int k = 0; k < 16; ++k) {
            float b[6];
            #pragma unroll
            for (int t = 0; t < 6; ++t) b[t] = sW[k][lane + 64 * t];
            #pragma unroll
            for (int e = 0; e < 8; ++e) {
                float a = sHf[wave * 8 + e][c * 16 + k];
                #pragma unroll
                for (int t = 0; t < 4; ++t) acc[e][t] = fmaf(a, b[t], acc[e][t]);
                acchn[e][0] = fmaf(a, b[4], acchn[e][0]);
                acchn[e][1] = fmaf(a, b[5], acchn[e][1]);
            }
        }
    }

    float bi[6], bh[6];
    #pragma unroll
    for (int t = 0; t < 6; ++t) { bi[t] = bih[lane + 64 * t]; bh[t] = bhh[lane + 64 * t]; }

    #pragma unroll
    for (int e = 0; e < 8; ++e) {
        size_t node = (size_t)(n0 + wave * 8 + e);
        #pragma unroll
        for (int p = 0; p < 2; ++p) {
            float r   = fast_sigmoid(acc[e][p]     + bi[p]     + bh[p]);
            float z   = fast_sigmoid(acc[e][2 + p] + bi[2 + p] + bh[2 + p]);
            float hn  = acchn[e][p] + bh[4 + p];
            float in_ = acc[e][4 + p] + bi[4 + p];
            float nn  = fast_tanh(in_ + r * hn);
            float h   = nf[node * 128 + lane + 64 * p];
            out[node * 128 + lane + 64 * p] = (1.f - z) * nn + z * h;
        }
    }
}

extern "C" void kernel_launch(void* const* d_in, const int* in_sizes, int n_in,
                              void* d_out, int out_size, void* d_ws, size_t ws_size,
                              hipStream_t stream)
{
    const float* nf  = (const float*)d_in[0];
    const float* ef  = (const float*)d_in[1];
    const int*   src = (const int*)d_in[2];
    const int*   dst = (const int*)d_in[3];
    const float* W1  = (const float*)d_in[6];
    const float* b1  = (const float*)d_in[7];
    const float* W2  = (const float*)d_in[8];
    const float* b2  = (const float*)d_in[9];
    const float* Wih = (const float*)d_in[10];
    const float* bih = (const float*)d_in[11];
    const float* Whh = (const float*)d_in[12];
    const float* bhh = (const float*)d_in[13];
    float* out = (float*)d_out;

    // ws layout (~34.3 MB): [u (aliases nf_bf)] | WihT | WhhT | W1bf | W2bf
    // nf_bf is only live during cvt_inputs->edge_mlp_mfma; u is written later
    // (attention) and read later (gru) — stream order makes the alias safe.
    char* ws = (char*)d_ws;
    u16*   nf_bf  = (u16*)ws;                          // 16,777,216 B
    float* u      = (float*)ws;                        // 33,554,432 B (aliases nf_bf)
    float* WihT   = (float*)(ws + 33554432);           //    393,216 B
    float* WhhT   = (float*)(ws + 33947648);           //    196,608 B
    u16*   W1bf   = (u16*)(ws + 34144256);             //     81,920 B
    u16*   W2bf   = (u16*)(ws + 34226176);             //     32,768 B

    hipMemsetAsync(d_out, 0, (size_t)N_NODES * 128 * 4, stream);   // m accumulator
    cvt_inputs<<<8248, 256, 0, stream>>>(nf, W1, W2, nf_bf, W1bf, W2bf);
    prep_weights<<<576, 256, 0, stream>>>(Wih, Whh, WihT, WhhT);
    edge_mlp_mfma<<<E_EDGES / 128, 256, 0, stream>>>(nf_bf, ef, src, dst, W1bf, b1, W2bf, b2, out);
    attention_kernel<<<64 * 2 * 8, 256, 0, stream>>>(nf, u);
    gru_kernel<<<N_NODES / 32, 256, 0, stream>>>(nf, u, WihT, bih, WhhT, bhh, out);
}

// Round 5
// 767.259 us; speedup vs baseline: 1.7385x; 1.7385x over previous
//
#include <hip/hip_runtime.h>
#include <cstdint>

#define N_NODES 65536
#define E_EDGES 524288

typedef unsigned short u16;
typedef unsigned int u32;
typedef __attribute__((ext_vector_type(8))) short bf16x8;
typedef __attribute__((ext_vector_type(4))) float f32x4;

__device__ __forceinline__ float fast_sigmoid(float x) { return 1.0f / (1.0f + __expf(-x)); }
__device__ __forceinline__ float fast_tanh(float x) { return 1.0f - 2.0f / (__expf(2.0f * x) + 1.0f); }

__device__ __forceinline__ u16 f2bf(float f) {
    u32 u = __builtin_bit_cast(u32, f);
    u32 r = u + 0x7fffu + ((u >> 16) & 1u);
    return (u16)(r >> 16);
}

// XOR swizzle: permute 16B slots within a row by (row&7) — kills stride-128/256/512B conflicts
#define SWZ(row, byte) ((byte) ^ (((row) & 7) << 4))

// ---------- prep: fp32->bf16 conversions ----------
__global__ void cvt_inputs(const float* __restrict__ nf, const float* __restrict__ W1,
                           const float* __restrict__ W2, const float* __restrict__ Wih,
                           const float* __restrict__ Whh,
                           u16* __restrict__ nf_bf, u16* __restrict__ W1bf, u16* __restrict__ W2bf,
                           u16* __restrict__ Wihbf, u16* __restrict__ Whhbf)
{
    int u = blockIdx.x * 256 + threadIdx.x;
    const float4* srcp; u16* dstp; int idx;
    if (u < 2097152)                 { srcp = (const float4*)nf;  dstp = nf_bf;  idx = u; }
    else if ((u -= 2097152) < 10240) { srcp = (const float4*)W1;  dstp = W1bf;  idx = u; }
    else if ((u -= 10240) < 4096)    { srcp = (const float4*)W2;  dstp = W2bf;  idx = u; }
    else if ((u -= 4096) < 24576)    { srcp = (const float4*)Wih; dstp = Wihbf; idx = u; }
    else if ((u -= 24576) < 12288)   { srcp = (const float4*)Whh; dstp = Whhbf; idx = u; }
    else return;
    float4 f = srcp[idx];
    uint2 pk;
    pk.x = (u32)f2bf(f.x) | ((u32)f2bf(f.y) << 16);
    pk.y = (u32)f2bf(f.z) | ((u32)f2bf(f.w) << 16);
    *(uint2*)(dstp + (size_t)idx * 4) = pk;
}

// ---------- edge MLP via bf16 MFMA + atomic scatter (validated round 3) ----------
__global__ __launch_bounds__(256) void edge_mlp_mfma(
    const u16* __restrict__ nf_bf, const float* __restrict__ ef,
    const int* __restrict__ src, const int* __restrict__ dst,
    const u16* __restrict__ W1bf, const float* __restrict__ b1,
    const u16* __restrict__ W2bf, const float* __restrict__ b2,
    float* __restrict__ m_out)
{
    __shared__ __align__(16) char smem[65536];
    __shared__ int sNode[2][128];
    char* sA   = smem;                      // [128][64] bf16 swz
    char* sB   = smem + 16384;              // [128][64] bf16 swz (W1 chunk)
    char* sHid = smem + 32768;              // [128][128] bf16 swz
    char* sB2  = smem;                      // [128][128] bf16 swz (W2)

    const int tid = threadIdx.x;
    const int lane = tid & 63;
    const int wv = tid >> 6;
    const int wm = wv >> 1, wn = wv & 1;
    const int q = lane >> 4, r16 = lane & 15;
    const int e0 = blockIdx.x * 128;

    if (tid < 128) sNode[0][tid] = src[e0 + tid];
    else           sNode[1][tid - 128] = dst[e0 + tid - 128];

    float b1v[4], b2v[4];
    #pragma unroll
    for (int ni = 0; ni < 4; ++ni) {
        int o = wn * 64 + ni * 16 + r16;
        b1v[ni] = b1[o];
        b2v[ni] = b2[o];
    }

    f32x4 acc[4][4] = {};
    __syncthreads();

    for (int c = 0; c < 5; ++c) {
        __syncthreads();
        if (c < 4) {
            const int half = (c & 1) * 64;
            const int* nodes = sNode[c >> 1];
            #pragma unroll
            for (int i = 0; i < 4; ++i) {
                int u = tid + i * 256;
                int e = u >> 3, part = u & 7;
                int node = nodes[e];
                bf16x8 v = *(const bf16x8*)(nf_bf + (size_t)node * 128 + half + part * 8);
                *(bf16x8*)(sA + SWZ(e, e * 128 + part * 16)) = v;
            }
        } else {
            #pragma unroll
            for (int i = 0; i < 8; ++i) {
                int u = tid + i * 256;
                int e = u >> 4, part = u & 15;
                float4 f = *(const float4*)(ef + (size_t)(e0 + e) * 64 + part * 4);
                uint2 pk;
                pk.x = (u32)f2bf(f.x) | ((u32)f2bf(f.y) << 16);
                pk.y = (u32)f2bf(f.z) | ((u32)f2bf(f.w) << 16);
                *(uint2*)(sA + SWZ(e, e * 128 + part * 8)) = pk;
            }
        }
        #pragma unroll
        for (int i = 0; i < 4; ++i) {
            int u = tid + i * 256;
            int o = u >> 3, part = u & 7;
            bf16x8 v = *(const bf16x8*)(W1bf + (size_t)o * 320 + c * 64 + part * 8);
            *(bf16x8*)(sB + SWZ(o, o * 128 + part * 16)) = v;
        }
        __syncthreads();
        #pragma unroll
        for (int ks = 0; ks < 2; ++ks) {
            bf16x8 af[4], bfr[4];
            #pragma unroll
            for (int mi = 0; mi < 4; ++mi) {
                int row = wm * 64 + mi * 16 + r16;
                af[mi] = *(const bf16x8*)(sA + SWZ(row, row * 128 + (ks * 32 + 8 * q) * 2));
            }
            #pragma unroll
            for (int ni = 0; ni < 4; ++ni) {
                int o = wn * 64 + ni * 16 + r16;
                bfr[ni] = *(const bf16x8*)(sB + SWZ(o, o * 128 + (ks * 32 + 8 * q) * 2));
            }
            #pragma unroll
            for (int mi = 0; mi < 4; ++mi)
                #pragma unroll
                for (int ni = 0; ni < 4; ++ni)
                    acc[mi][ni] = __builtin_amdgcn_mfma_f32_16x16x32_bf16(af[mi], bfr[ni], acc[mi][ni], 0, 0, 0);
        }
    }

    #pragma unroll
    for (int mi = 0; mi < 4; ++mi)
        #pragma unroll
        for (int ni = 0; ni < 4; ++ni)
            #pragma unroll
            for (int rr = 0; rr < 4; ++rr) {
                int e = wm * 64 + mi * 16 + 4 * q + rr;
                int h = wn * 64 + ni * 16 + r16;
                float v = fmaxf(acc[mi][ni][rr] + b1v[ni], 0.f);
                *(u16*)(sHid + SWZ(e, e * 256 + h * 2)) = f2bf(v);
            }
    __syncthreads();

    #pragma unroll
    for (int i = 0; i < 8; ++i) {
        int u = tid + i * 256;
        int o = u >> 4, part = u & 15;
        bf16x8 v = *(const bf16x8*)(W2bf + (size_t)o * 128 + part * 8);
        *(bf16x8*)(sB2 + SWZ(o, o * 256 + part * 16)) = v;
    }
    __syncthreads();

    f32x4 acc2[4][4] = {};
    #pragma unroll
    for (int ks = 0; ks < 4; ++ks) {
        bf16x8 af[4], bfr[4];
        #pragma unroll
        for (int mi = 0; mi < 4; ++mi) {
            int row = wm * 64 + mi * 16 + r16;
            af[mi] = *(const bf16x8*)(sHid + SWZ(row, row * 256 + (ks * 32 + 8 * q) * 2));
        }
        #pragma unroll
        for (int ni = 0; ni < 4; ++ni) {
            int o = wn * 64 + ni * 16 + r16;
            bfr[ni] = *(const bf16x8*)(sB2 + SWZ(o, o * 256 + (ks * 32 + 8 * q) * 2));
        }
        #pragma unroll
        for (int mi = 0; mi < 4; ++mi)
            #pragma unroll
            for (int ni = 0; ni < 4; ++ni)
                acc2[mi][ni] = __builtin_amdgcn_mfma_f32_16x16x32_bf16(af[mi], bfr[ni], acc2[mi][ni], 0, 0, 0);
    }

    #pragma unroll
    for (int mi = 0; mi < 4; ++mi) {
        #pragma unroll
        for (int rr = 0; rr < 4; ++rr) {
            int e = wm * 64 + mi * 16 + 4 * q + rr;
            int d = sNode[1][e];
            float* mrow = m_out + (size_t)d * 128;
            #pragma unroll
            for (int ni = 0; ni < 4; ++ni) {
                int o = wn * 64 + ni * 16 + r16;
                unsafeAtomicAdd(mrow + o, acc2[mi][ni][rr] + b2v[ni]);
            }
        }
    }
}

// ---------- cross-graph attention: bf16 MFMA flash (single pass, online softmax) ----------
// grid: qtile(8) x side(2) x pair(64) = 1024 blocks, 256 thr = 4 waves x 16 q-rows.
// Per K-tile (64 keys): stage K [key][d] swz + KT [d][key] swz; S = Q@K^T via mfma;
// softmax stats via 16-lane shfl reduce; P -> per-wave LDS; O += P@V via mfma (B = KT).
__global__ __launch_bounds__(256) void attn_mfma(
    const u16* __restrict__ nf_bf, const float* __restrict__ nf,
    u16* __restrict__ u_bf)
{
    __shared__ __align__(16) char sK[16384];   // [64][128] bf16 swz
    __shared__ __align__(16) char sKT[16384];  // [128][64] bf16 swz
    __shared__ __align__(16) char sP[8192];    // per wave: [16][64] bf16 swz

    const int tid = threadIdx.x;
    const int lane = tid & 63;
    const int wave = tid >> 6;
    const int l4 = lane >> 4, l15 = lane & 15;

    const int bid = blockIdx.x;
    const int qt = bid & 7;
    const int side = (bid >> 3) & 1;
    const int pair = bid >> 4;

    const size_t qbase = (size_t)pair * 1024 + (size_t)side * 512 + qt * 64;
    const size_t kbase = (size_t)pair * 1024 + (size_t)(1 - side) * 512;

    // Q A-frags held in registers (row = l15 of wave's 16, k = kc*32 + l4*8)
    bf16x8 aq[4];
    const int qrow = wave * 16 + l15;
    #pragma unroll
    for (int kc = 0; kc < 4; ++kc)
        aq[kc] = *(const bf16x8*)(nf_bf + (qbase + qrow) * 128 + kc * 32 + l4 * 8);

    f32x4 o_acc[8] = {};
    float m_r[4], l_r[4];
    #pragma unroll
    for (int r = 0; r < 4; ++r) { m_r[r] = -3.0e38f; l_r[r] = 0.f; }

    for (int kt = 0; kt < 8; ++kt) {
        __syncthreads();   // previous tile's K/KT reads done
        #pragma unroll
        for (int i = 0; i < 4; ++i) {
            int u = tid + i * 256;
            int key = u & 63;
            int d8 = u >> 6;
            bf16x8 v = *(const bf16x8*)(nf_bf + (kbase + kt * 64 + key) * 128 + d8 * 8);
            *(bf16x8*)(sK + SWZ(key, key * 256 + d8 * 16)) = v;
            #pragma unroll
            for (int j = 0; j < 8; ++j) {        // transpose write: row d, contiguous keys
                int d = d8 * 8 + j;
                *(u16*)(sKT + SWZ(d, d * 128 + key * 2)) = (u16)v[j];
            }
        }
        __syncthreads();

        // S = Q @ K^T  (M=16 q-rows, N=64 keys)
        f32x4 s_acc[4] = {};
        #pragma unroll
        for (int nb = 0; nb < 4; ++nb) {
            #pragma unroll
            for (int kc = 0; kc < 4; ++kc) {
                int krow = nb * 16 + l15;
                bf16x8 bk = *(const bf16x8*)(sK + SWZ(krow, krow * 256 + (kc * 32 + l4 * 8) * 2));
                s_acc[nb] = __builtin_amdgcn_mfma_f32_16x16x32_bf16(aq[kc], bk, s_acc[nb], 0, 0, 0);
            }
        }

        // online softmax: stat rows = l4*4 + r; reduce over the 16 key-cols (lanes l15)
        float rm[4];
        #pragma unroll
        for (int r = 0; r < 4; ++r)
            rm[r] = fmaxf(fmaxf(s_acc[0][r], s_acc[1][r]), fmaxf(s_acc[2][r], s_acc[3][r]));
        #pragma unroll
        for (int w = 1; w < 16; w <<= 1)
            #pragma unroll
            for (int r = 0; r < 4; ++r) rm[r] = fmaxf(rm[r], __shfl_xor(rm[r], w));

        float sc[4], rs[4];
        #pragma unroll
        for (int r = 0; r < 4; ++r) {
            float mn = fmaxf(m_r[r], rm[r]);
            sc[r] = __expf(m_r[r] - mn);
            m_r[r] = mn;
            rs[r] = 0.f;
        }
        #pragma unroll
        for (int nb = 0; nb < 4; ++nb)
            #pragma unroll
            for (int r = 0; r < 4; ++r) {
                float p = __expf(s_acc[nb][r] - m_r[r]);
                rs[r] += p;
                int prow = l4 * 4 + r;
                *(u16*)(sP + wave * 2048 + SWZ(prow, prow * 128 + (nb * 16 + l15) * 2)) = f2bf(p);
            }
        #pragma unroll
        for (int w = 1; w < 16; w <<= 1)
            #pragma unroll
            for (int r = 0; r < 4; ++r) rs[r] += __shfl_xor(rs[r], w);
        #pragma unroll
        for (int r = 0; r < 4; ++r) l_r[r] = l_r[r] * sc[r] + rs[r];

        #pragma unroll
        for (int df = 0; df < 8; ++df)
            #pragma unroll
            for (int r = 0; r < 4; ++r) o_acc[df][r] *= sc[r];

        // O += P @ V (V = K; A = P per-wave, B-frag rows from KT[d][key])
        // same-wave LDS write->read: compiler inserts lgkmcnt waits, no barrier needed
        #pragma unroll
        for (int kc2 = 0; kc2 < 2; ++kc2) {
            bf16x8 ap = *(const bf16x8*)(sP + wave * 2048 + SWZ(l15, l15 * 128 + (kc2 * 32 + l4 * 8) * 2));
            #pragma unroll
            for (int df = 0; df < 8; ++df) {
                int drow = df * 16 + l15;
                bf16x8 bv = *(const bf16x8*)(sKT + SWZ(drow, drow * 128 + (kc2 * 32 + l4 * 8) * 2));
                o_acc[df] = __builtin_amdgcn_mfma_f32_16x16x32_bf16(ap, bv, o_acc[df], 0, 0, 0);
            }
        }
    }

    // u = x - O/l  (x in fp32), store bf16
    #pragma unroll
    for (int df = 0; df < 8; ++df)
        #pragma unroll
        for (int r = 0; r < 4; ++r) {
            size_t qg = qbase + wave * 16 + l4 * 4 + r;
            int d = df * 16 + l15;
            float val = nf[qg * 128 + d] - o_acc[df][r] / l_r[r];
            u_bf[qg * 128 + d] = f2bf(val);
        }
}

// ---------- GRU via bf16 MFMA ----------
// 64 nodes/block, 4 waves x 16 nodes; each wave covers all 384 gate-outs (24 N-frags).
// A (xin=[m|u], h) staged swizzled in LDS; W B-frags read directly from global bf16 (L2-hot).
__global__ __launch_bounds__(256) void gru_mfma(
    const u16* __restrict__ nf_bf, const float* __restrict__ nf,
    const u16* __restrict__ u_bf,
    const u16* __restrict__ Wihbf, const float* __restrict__ bih,
    const u16* __restrict__ Whhbf, const float* __restrict__ bhh,
    float* __restrict__ out)
{
    __shared__ __align__(16) char sX[32768];  // [64][256] bf16 swz (xin)
    __shared__ __align__(16) char sH[16384];  // [64][128] bf16 swz

    const int tid = threadIdx.x;
    const int lane = tid & 63;
    const int wave = tid >> 6;
    const int l4 = lane >> 4, l15 = lane & 15;
    const int n0 = blockIdx.x * 64;

    // stage xin[:,0:128] = m (fp32 from out, cvt)
    #pragma unroll
    for (int i = 0; i < 8; ++i) {
        int u = tid + i * 256;
        int node = u >> 5, c4 = u & 31;
        float4 f = *(const float4*)(out + (size_t)(n0 + node) * 128 + c4 * 4);
        uint2 pk;
        pk.x = (u32)f2bf(f.x) | ((u32)f2bf(f.y) << 16);
        pk.y = (u32)f2bf(f.z) | ((u32)f2bf(f.w) << 16);
        *(uint2*)(sX + SWZ(node, node * 512 + c4 * 8)) = pk;
    }
    // stage xin[:,128:256] = u (bf16) and h (bf16)
    #pragma unroll
    for (int i = 0; i < 4; ++i) {
        int u = tid + i * 256;
        int node = u >> 4, p8 = u & 15;
        bf16x8 v = *(const bf16x8*)(u_bf + (size_t)(n0 + node) * 128 + p8 * 8);
        *(bf16x8*)(sX + SWZ(node, node * 512 + 256 + p8 * 16)) = v;
        bf16x8 h = *(const bf16x8*)(nf_bf + (size_t)(n0 + node) * 128 + p8 * 8);
        *(bf16x8*)(sH + SWZ(node, node * 256 + p8 * 16)) = h;
    }
    __syncthreads();

    f32x4 acc[24] = {};    // r: 0..7, z: 8..15, i_n: 16..23 (r,z merged with gh)
    f32x4 acchn[8] = {};   // h_n separate

    const int arow = wave * 16 + l15;

    // gi: xin @ Wih^T, K=256
    #pragma unroll
    for (int c = 0; c < 8; ++c) {
        bf16x8 a = *(const bf16x8*)(sX + SWZ(arow, arow * 512 + (c * 32 + l4 * 8) * 2));
        #pragma unroll
        for (int nf2 = 0; nf2 < 24; ++nf2) {
            bf16x8 b = *(const bf16x8*)(Wihbf + (size_t)(nf2 * 16 + l15) * 256 + c * 32 + l4 * 8);
            acc[nf2] = __builtin_amdgcn_mfma_f32_16x16x32_bf16(a, b, acc[nf2], 0, 0, 0);
        }
    }
    // gh: h @ Whh^T, K=128 (r,z into acc; h_n into acchn)
    #pragma unroll
    for (int c = 0; c < 4; ++c) {
        bf16x8 a = *(const bf16x8*)(sH + SWZ(arow, arow * 256 + (c * 32 + l4 * 8) * 2));
        #pragma unroll
        for (int nf2 = 0; nf2 < 16; ++nf2) {
            bf16x8 b = *(const bf16x8*)(Whhbf + (size_t)(nf2 * 16 + l15) * 128 + c * 32 + l4 * 8);
            acc[nf2] = __builtin_amdgcn_mfma_f32_16x16x32_bf16(a, b, acc[nf2], 0, 0, 0);
        }
        #pragma unroll
        for (int nf2 = 16; nf2 < 24; ++nf2) {
            bf16x8 b = *(const bf16x8*)(Whhbf + (size_t)(nf2 * 16 + l15) * 128 + c * 32 + l4 * 8);
            acchn[nf2 - 16] = __builtin_amdgcn_mfma_f32_16x16x32_bf16(a, b, acchn[nf2 - 16], 0, 0, 0);
        }
    }

    // epilogue: gates + blend (C/D: col d = df*16+l15, row node = l4*4+r)
    #pragma unroll
    for (int df = 0; df < 8; ++df) {
        int d = df * 16 + l15;
        float bir = bih[d],       bhr = bhh[d];
        float biz = bih[128 + d], bhz = bhh[128 + d];
        float bin = bih[256 + d], bhn = bhh[256 + d];
        #pragma unroll
        for (int r = 0; r < 4; ++r) {
            size_t node = (size_t)n0 + wave * 16 + l4 * 4 + r;
            float rg = fast_sigmoid(acc[df][r] + bir + bhr);
            float zg = fast_sigmoid(acc[8 + df][r] + biz + bhz);
            float ng = fast_tanh(acc[16 + df][r] + bin + rg * (acchn[df][r] + bhn));
            float h  = nf[node * 128 + d];
            out[node * 128 + d] = (1.f - zg) * ng + zg * h;
        }
    }
}

extern "C" void kernel_launch(void* const* d_in, const int* in_sizes, int n_in,
                              void* d_out, int out_size, void* d_ws, size_t ws_size,
                              hipStream_t stream)
{
    const float* nf  = (const float*)d_in[0];
    const float* ef  = (const float*)d_in[1];
    const int*   src = (const int*)d_in[2];
    const int*   dst = (const int*)d_in[3];
    const float* W1  = (const float*)d_in[6];
    const float* b1  = (const float*)d_in[7];
    const float* W2  = (const float*)d_in[8];
    const float* b2  = (const float*)d_in[9];
    const float* Wih = (const float*)d_in[10];
    const float* bih = (const float*)d_in[11];
    const float* Whh = (const float*)d_in[12];
    const float* bhh = (const float*)d_in[13];
    float* out = (float*)d_out;

    // ws layout (~34.0 MB, within the 34.37 MB proven in round 1):
    char* ws = (char*)d_ws;
    u16* nf_bf = (u16*)ws;                       // 16,777,216 B
    u16* u_bf  = (u16*)(ws + 16777216);          // 16,777,216 B
    u16* W1bf  = (u16*)(ws + 33554432);          //     81,920 B
    u16* W2bf  = (u16*)(ws + 33636352);          //     32,768 B
    u16* Wihbf = (u16*)(ws + 33669120);          //    196,608 B
    u16* Whhbf = (u16*)(ws + 33865728);          //     98,304 B

    hipMemsetAsync(d_out, 0, (size_t)N_NODES * 128 * 4, stream);   // m accumulator
    cvt_inputs<<<8392, 256, 0, stream>>>(nf, W1, W2, Wih, Whh, nf_bf, W1bf, W2bf, Wihbf, Whhbf);
    edge_mlp_mfma<<<E_EDGES / 128, 256, 0, stream>>>(nf_bf, ef, src, dst, W1bf, b1, W2bf, b2, out);
    attn_mfma<<<64 * 2 * 8, 256, 0, stream>>>(nf_bf, nf, u_bf);
    gru_mfma<<<N_NODES / 64, 256, 0, stream>>>(nf_bf, nf, u_bf, Wihbf, bih, Whhbf, bhh, out);
}